// Round 4
// baseline (8254.881 us; speedup 1.0000x reference)
//
#include <hip/hip_runtime.h>
#include <stdint.h>

#define DD 1024   // D
#define SS 1024   // S
#define NBS 32    // scan blocks (co-resident: 32 <= 256 CUs)

typedef __attribute__((ext_vector_type(8))) __bf16 bf16x8;
typedef __attribute__((ext_vector_type(4))) float f32x4;

union Frag { uint4 u; bf16x8 b; };

__device__ __forceinline__ float bf2f(ushort u){ union{uint32_t i; float f;} c; c.i = ((uint32_t)u)<<16; return c.f; }
__device__ __forceinline__ float bflo(uint32_t p){ union{uint32_t i; float f;} c; c.i = p<<16; return c.f; }
__device__ __forceinline__ float bfhi(uint32_t p){ union{uint32_t i; float f;} c; c.i = p & 0xffff0000u; return c.f; }
__device__ __forceinline__ ushort f2bf(float f){
  union{float f; uint32_t u;} c; c.f = f;
  uint32_t u = c.u;
  return (ushort)((u + 0x7fffu + ((u>>16)&1u)) >> 16);   // RNE
}

// ------------------------------------------------------------------- cast ---
__global__ __launch_bounds__(256) void cast_k(const float* __restrict__ s,
    ushort* __restrict__ d, int n)
{
  int i = (blockIdx.x*256 + threadIdx.x)*4;
  if (i >= n) return;
  float4 v = *(const float4*)(s+i);
  ushort4 o; o.x=f2bf(v.x); o.y=f2bf(v.y); o.z=f2bf(v.z); o.w=f2bf(v.w);
  *(ushort4*)(d+i) = o;
}

// ---------------------------------------------------------------- rmsnorm ---
__global__ __launch_bounds__(256) void rmsnorm_k(const float* __restrict__ X,
    const float* __restrict__ w, ushort* __restrict__ out)
{
  const int row = blockIdx.x, t = threadIdx.x;
  const float* x = X + (size_t)row*DD;
  float xs[4]; float s = 0.f;
  #pragma unroll
  for (int i=0;i<4;i++){ float v = x[t + i*256]; xs[i]=v; s += v*v; }
  #pragma unroll
  for (int off=32; off>0; off>>=1) s += __shfl_xor(s, off, 64);
  __shared__ float sred[4];
  if ((t&63)==0) sred[t>>6] = s;
  __syncthreads();
  s = sred[0]+sred[1]+sred[2]+sred[3];
  float inv = 1.f/(sqrtf(s)*0.03125f + 1e-6f);   // /sqrt(1024), + eps
  #pragma unroll
  for (int i=0;i<4;i++){
    int c2 = t + i*256;
    out[(size_t)row*DD + c2] = f2bf(xs[i]*inv*w[c2]);
  }
}

// ---------------------------------------------------------- MFMA GEMM (BT) --
enum { ACT_NONE=0, ACT_RELU=1, ACT_SIG=2, ACT_GELU=3 };
enum { EPI_B16=0, EPI_DUAL=1, EPI_F32=2, EPI_Y=3, EPI_OUT=4 };

template<int ACT, int EPI>
__global__ __launch_bounds__(256) void gemm_bt(
    const ushort* __restrict__ A, const ushort* __restrict__ W,
    const float* __restrict__ bias, int N, int K,
    ushort* __restrict__ Ob, float* __restrict__ Of,
    const float* __restrict__ X32, const ushort* __restrict__ H16,
    const float* __restrict__ Yf)
{
  __shared__ __align__(16) ushort At[128*32];
  __shared__ __align__(16) ushort Wt[128*32];
  const int tid = threadIdx.x;
  const int wave = tid >> 6, lane = tid & 63;
  const int quad = lane >> 4, l16 = lane & 15;
  const int wr = wave >> 1, wc = wave & 1;
  const int m0 = blockIdx.x * 128, n0 = blockIdx.y * 128;

  f32x4 acc[4][4];
  const f32x4 vz = {0.f,0.f,0.f,0.f};
  #pragma unroll
  for (int i=0;i<4;i++)
    #pragma unroll
    for (int j=0;j<4;j++) acc[i][j] = vz;

  const ushort* gA = A + (size_t)(m0 + wave*32 + (lane>>2))*K + (lane&3)*8;
  const ushort* gW = W + (size_t)(n0 + wave*32 + (lane>>2))*K + (lane&3)*8;
  ushort* lA = At + wave*1024 + lane*8;
  ushort* lW = Wt + wave*1024 + lane*8;

  for (int ko = 0; ko < K; ko += 32) {
    uint4 va  = *(const uint4*)(gA + ko);
    uint4 va2 = *(const uint4*)(gA + ko + (size_t)16*K);
    uint4 vw  = *(const uint4*)(gW + ko);
    uint4 vw2 = *(const uint4*)(gW + ko + (size_t)16*K);
    __syncthreads();
    *(uint4*)lA          = va;
    *(uint4*)(lA + 512)  = va2;
    *(uint4*)lW          = vw;
    *(uint4*)(lW + 512)  = vw2;
    __syncthreads();
    Frag af[4], bfr[4];
    #pragma unroll
    for (int mi=0;mi<4;mi++)
      af[mi].u = *(const uint4*)&At[(wr*64 + mi*16 + l16)*32 + quad*8];
    #pragma unroll
    for (int ni=0;ni<4;ni++)
      bfr[ni].u = *(const uint4*)&Wt[(wc*64 + ni*16 + l16)*32 + quad*8];
    #pragma unroll
    for (int mi=0;mi<4;mi++)
      #pragma unroll
      for (int ni=0;ni<4;ni++)
        acc[mi][ni] = __builtin_amdgcn_mfma_f32_16x16x32_bf16(af[mi].b, bfr[ni].b, acc[mi][ni], 0,0,0);
  }

  float bia[4];
  #pragma unroll
  for (int ni=0;ni<4;ni++) bia[ni] = bias[n0 + wc*64 + ni*16 + l16];
  #pragma unroll
  for (int mi=0;mi<4;mi++) {
    const int row0 = m0 + wr*64 + mi*16 + quad*4;
    #pragma unroll
    for (int ni=0;ni<4;ni++) {
      const int col = n0 + wc*64 + ni*16 + l16;
      #pragma unroll
      for (int r=0;r<4;r++) {
        float vx = acc[mi][ni][r] + bia[ni];
        if (ACT == ACT_RELU) vx = fmaxf(vx, 0.f);
        else if (ACT == ACT_SIG) {
          vx = 1.f/(1.f+__expf(-vx));
          vx = fminf(fmaxf(vx, 1e-6f), 1.f-1e-6f);
        } else if (ACT == ACT_GELU) {
          float ci = 0.7978845608028654f*(vx + 0.044715f*vx*vx*vx);
          float th = 1.f - 2.f/(1.f + __expf(2.f*ci));
          vx = 0.5f*vx*(1.f+th);
        }
        size_t idx = (size_t)(row0 + r)*N + col;
        if (EPI == EPI_B16)      Ob[idx] = f2bf(vx);
        else if (EPI == EPI_DUAL){ Ob[idx] = f2bf(vx); Of[idx] = vx; }
        else if (EPI == EPI_F32)  Of[idx] = vx;
        else if (EPI == EPI_Y)    Of[idx] = vx + X32[idx] + bf2f(H16[idx]);
        else                      Of[idx] = vx + Yf[idx];
      }
    }
  }
}

// ------------------------------------------------------------- attention ----
__global__ __launch_bounds__(256) void attn_k(const ushort* __restrict__ q,
  const ushort* __restrict__ k, const ushort* __restrict__ v, ushort* __restrict__ ao)
{
  __shared__ __align__(16) ushort Ks[64*64];
  __shared__ __align__(16) ushort Vs[64*64];
  __shared__ float Ps[64*65];
  const int qt = blockIdx.x, bh = blockIdx.y;
  const int b = bh >> 4, h = bh & 15;
  const int t = threadIdx.x, r = t >> 2, seg = t & 3;
  const ushort* qrow = q + ((size_t)(b*SS + qt*64 + r))*DD + h*64;
  float qr[64];
  #pragma unroll
  for (int i=0;i<64;i+=8){
    uint4 u = *(const uint4*)(qrow + i);
    qr[i+0]=bflo(u.x); qr[i+1]=bfhi(u.x); qr[i+2]=bflo(u.y); qr[i+3]=bfhi(u.y);
    qr[i+4]=bflo(u.z); qr[i+5]=bfhi(u.z); qr[i+6]=bflo(u.w); qr[i+7]=bfhi(u.w);
  }
  float o[16];
  #pragma unroll
  for (int i=0;i<16;i++) o[i]=0.f;
  float mrun = -1e30f, lrun = 0.f;
  const int jrow = t >> 3, jch = t & 7;
  for (int kt=0; kt<16; kt++) {
    __syncthreads();
    const ushort* kg = k + ((size_t)(b*SS + kt*64))*DD + h*64;
    const ushort* vg = v + ((size_t)(b*SS + kt*64))*DD + h*64;
    #pragma unroll
    for (int part=0; part<2; part++){
      int j = jrow + part*32;
      *(uint4*)&Ks[j*64 + jch*8] = *(const uint4*)(kg + (size_t)j*DD + jch*8);
      *(uint4*)&Vs[j*64 + jch*8] = *(const uint4*)(vg + (size_t)j*DD + jch*8);
    }
    __syncthreads();
    float sc[16];
    #pragma unroll
    for (int jj=0;jj<16;jj++){
      int j = seg*16 + jj;
      float s_ = 0.f;
      #pragma unroll
      for (int i=0;i<64;i+=8){
        uint4 u = *(const uint4*)&Ks[j*64+i];
        s_ = fmaf(qr[i+0], bflo(u.x), s_); s_ = fmaf(qr[i+1], bfhi(u.x), s_);
        s_ = fmaf(qr[i+2], bflo(u.y), s_); s_ = fmaf(qr[i+3], bfhi(u.y), s_);
        s_ = fmaf(qr[i+4], bflo(u.z), s_); s_ = fmaf(qr[i+5], bfhi(u.z), s_);
        s_ = fmaf(qr[i+6], bflo(u.w), s_); s_ = fmaf(qr[i+7], bfhi(u.w), s_);
      }
      sc[jj] = s_ * 0.125f;
    }
    float mx = sc[0];
    #pragma unroll
    for (int jj=1;jj<16;jj++) mx = fmaxf(mx, sc[jj]);
    mx = fmaxf(mx, __shfl_xor(mx, 1, 64));
    mx = fmaxf(mx, __shfl_xor(mx, 2, 64));
    float mnew = fmaxf(mrun, mx);
    float psum = 0.f;
    #pragma unroll
    for (int jj=0;jj<16;jj++){
      float p = __expf(sc[jj]-mnew);
      Ps[r*65 + seg*16 + jj] = p;
      psum += p;
    }
    psum += __shfl_xor(psum, 1, 64);
    psum += __shfl_xor(psum, 2, 64);
    float alpha = __expf(mrun - mnew);
    lrun = lrun*alpha + psum;
    mrun = mnew;
    #pragma unroll
    for (int i=0;i<16;i++) o[i] *= alpha;
    __syncthreads();
    #pragma unroll 4
    for (int j=0;j<64;j++){
      float pj = Ps[r*65 + j];
      uint4 u0 = *(const uint4*)&Vs[j*64 + seg*16];
      uint4 u1 = *(const uint4*)&Vs[j*64 + seg*16 + 8];
      o[ 0]=fmaf(pj,bflo(u0.x),o[ 0]); o[ 1]=fmaf(pj,bfhi(u0.x),o[ 1]);
      o[ 2]=fmaf(pj,bflo(u0.y),o[ 2]); o[ 3]=fmaf(pj,bfhi(u0.y),o[ 3]);
      o[ 4]=fmaf(pj,bflo(u0.z),o[ 4]); o[ 5]=fmaf(pj,bfhi(u0.z),o[ 5]);
      o[ 6]=fmaf(pj,bflo(u0.w),o[ 6]); o[ 7]=fmaf(pj,bfhi(u0.w),o[ 7]);
      o[ 8]=fmaf(pj,bflo(u1.x),o[ 8]); o[ 9]=fmaf(pj,bfhi(u1.x),o[ 9]);
      o[10]=fmaf(pj,bflo(u1.y),o[10]); o[11]=fmaf(pj,bfhi(u1.y),o[11]);
      o[12]=fmaf(pj,bflo(u1.z),o[12]); o[13]=fmaf(pj,bfhi(u1.z),o[13]);
      o[14]=fmaf(pj,bflo(u1.w),o[14]); o[15]=fmaf(pj,bfhi(u1.w),o[15]);
    }
  }
  float invl = 1.f/lrun;
  ushort* orow = ao + ((size_t)(b*SS + qt*64 + r))*DD + h*64 + seg*16;
  #pragma unroll
  for (int i=0;i<16;i++) orow[i] = f2bf(o[i]*invl);
}

// ----------------------------------------------------------------- scan -----
// h_t = z_t * sigmoid(Wg h_{t-1} + bg) + gamma_t * h_{t-1}. Round-4:
//  - flag-array barrier: 1 release store/block to its own 64B line; readers
//    poll all 32 flags with ONE wave-vector load + ballot (no RMW serialization)
//  - XOR-swizzled Hs (bank bits ^= c) kills the 16-way B-frag conflicts
//  - 8B agent-atomic staging loads; plain (cached) hseq stores
__global__ __launch_bounds__(256) void scan_k(
    const ushort* __restrict__ Wgb, const float* __restrict__ bg,
    const float* __restrict__ z32, const float* __restrict__ gm32,
    ushort* __restrict__ hseq, ushort* __restrict__ hstate, // 2 x [4][1024] bf16
    unsigned int* __restrict__ flags)                        // 32 x 16 dwords
{
  const int blk = blockIdx.x, t = threadIdx.x;
  const int wave = t>>6, lane = t&63, quad = lane>>4, c = lane&15;
  const int mt = wave & 1, kh = wave >> 1;
  const int nbase = blk*32 + mt*16;
  const bool epi = (kh == 0) && (c < 4);
  const int n0w = nbase + quad*4;
  Frag a[16];                                   // Wg A-frags, loop-invariant
  {
    const ushort* wrow = Wgb + (size_t)(nbase + c)*DD + kh*512 + quad*8;
    #pragma unroll
    for (int kt=0;kt<16;kt++) a[kt].u = *(const uint4*)(wrow + kt*32);
  }
  float bgv[4];
  #pragma unroll
  for (int r=0;r<4;r++) bgv[r] = bg[nbase + quad*4 + r];
  __shared__ __align__(16) ushort Hs[4096];     // swizzled h_{t-1}
  __shared__ float redbuf[2][64][5];
  const int cb = c & 3;                         // in-bounds base for all lanes
  const int cx = (c & 7) << 3;                  // bank-group XOR key

  for (int st=0; st<SS; st++) {
    // prefetch z/gamma for this step (independent of the barrier)
    float zr[4], gr[4];
    if (epi) {
      float4 z4 = *(const float4*)(z32  + ((size_t)c*SS + st)*DD + n0w);
      float4 g4 = *(const float4*)(gm32 + ((size_t)c*SS + st)*DD + n0w);
      zr[0]=z4.x; zr[1]=z4.y; zr[2]=z4.z; zr[3]=z4.w;
      gr[0]=g4.x; gr[1]=g4.y; gr[2]=g4.z; gr[3]=g4.w;
    }
    if (st > 0) {
      if (t < 64) {                      // wave 0 polls all 32 flags at once
        const unsigned int* fp = flags + ((t & 31) << 4);
        for (;;) {
          unsigned v = __hip_atomic_load(fp, __ATOMIC_RELAXED, __HIP_MEMORY_SCOPE_AGENT);
          if (__ballot(v < (unsigned)st) == 0ull) break;
          __builtin_amdgcn_s_sleep(1);
        }
      }
      __syncthreads();
      // stage h_{t-1} into LDS (swizzled) via 8B agent atomics (L1/L2-bypass)
      const unsigned long long* hrd = (const unsigned long long*)(hstate + ((st+1)&1)*4096);
      unsigned long long* hsq = (unsigned long long*)Hs;
      #pragma unroll
      for (int i=0;i<4;i++){
        unsigned long long qv = __hip_atomic_load(hrd + t + i*256, __ATOMIC_RELAXED, __HIP_MEMORY_SCOPE_AGENT);
        hsq[(i<<8) | (t ^ (i<<1))] = qv;   // qword swizzle == ushort inner ^ (c<<3)
      }
      __syncthreads();
    }
    f32x4 acc = {0.f,0.f,0.f,0.f};
    if (st > 0) {
      f32x4 acc1 = {0.f,0.f,0.f,0.f};
      const uint4 z4 = make_uint4(0u,0u,0u,0u);
      #pragma unroll
      for (int kt=0;kt<16;kt+=2) {
        Frag b0, b1;
        b0.u = *(const uint4*)&Hs[cb*1024 + ((kh*512 + (kt  )*32 + quad*8) ^ cx)];
        b1.u = *(const uint4*)&Hs[cb*1024 + ((kh*512 + (kt+1)*32 + quad*8) ^ cx)];
        b0.u = (c<4) ? b0.u : z4;
        b1.u = (c<4) ? b1.u : z4;
        acc  = __builtin_amdgcn_mfma_f32_16x16x32_bf16(a[kt  ].b, b0.b, acc,  0,0,0);
        acc1 = __builtin_amdgcn_mfma_f32_16x16x32_bf16(a[kt+1].b, b1.b, acc1, 0,0,0);
      }
      #pragma unroll
      for (int r=0;r<4;r++) acc[r] += acc1[r];
    }
    if (kh == 1) {
      #pragma unroll
      for (int r=0;r<4;r++) redbuf[mt][lane][r] = acc[r];
    }
    __syncthreads();
    if (epi) {
      ushort hb[4];
      #pragma unroll
      for (int r=0;r<4;r++) {
        float g = acc[r] + redbuf[mt][lane][r] + bgv[r];
        g = 1.f/(1.f+__expf(-g));
        float hp = (st>0) ? bf2f(Hs[cb*1024 + ((n0w + r) ^ cx)]) : 0.f;
        hb[r] = f2bf(zr[r]*g + gr[r]*hp);
      }
      uint32_t p0 = (uint32_t)hb[0] | ((uint32_t)hb[1]<<16);
      uint32_t p1 = (uint32_t)hb[2] | ((uint32_t)hb[3]<<16);
      uint32_t* hwd = (uint32_t*)(hstate + (st&1)*4096);
      int di = (c*1024 + n0w) >> 1;
      __hip_atomic_store(hwd + di,     p0, __ATOMIC_RELAXED, __HIP_MEMORY_SCOPE_AGENT);
      __hip_atomic_store(hwd + di + 1, p1, __ATOMIC_RELAXED, __HIP_MEMORY_SCOPE_AGENT);
      uint32_t* sq = (uint32_t*)(hseq + ((size_t)c*SS + st)*DD + n0w);
      sq[0] = p0; sq[1] = p1;            // cached store: stays in L2
    }
    __syncthreads();                     // drains each wave's stores (vmcnt 0)
    if (t == 0)
      __hip_atomic_store(flags + (blk<<4), (unsigned)(st+1),
                         __ATOMIC_RELEASE, __HIP_MEMORY_SCOPE_AGENT);
  }
}

// --------------------------------------------------------------- launch -----
extern "C" void kernel_launch(void* const* d_in, const int* in_sizes, int n_in,
                              void* d_out, int out_size, void* d_ws, size_t ws_size,
                              hipStream_t stream)
{
  const float* x   = (const float*)d_in[0];
  const float* n1w = (const float*)d_in[1];
  const float* Wq  = (const float*)d_in[2];
  const float* bq  = (const float*)d_in[3];
  const float* Wk  = (const float*)d_in[4];
  const float* bk  = (const float*)d_in[5];
  const float* Wv  = (const float*)d_in[6];
  const float* bv  = (const float*)d_in[7];
  const float* Wz  = (const float*)d_in[8];
  const float* bz  = (const float*)d_in[9];
  const float* Wg_ = (const float*)d_in[10];
  const float* bg  = (const float*)d_in[11];
  const float* gdw = (const float*)d_in[12];
  const float* gdb = (const float*)d_in[13];
  const float* guw = (const float*)d_in[14];
  const float* gub = (const float*)d_in[15];
  const float* Wo  = (const float*)d_in[16];
  const float* bo  = (const float*)d_in[17];
  const float* n2w = (const float*)d_in[18];
  const float* f1w = (const float*)d_in[19];
  const float* f1b = (const float*)d_in[20];
  const float* f2w = (const float*)d_in[21];
  const float* f2b = (const float*)d_in[22];

  char* ws = (char*)d_ws;
  const size_t MB = (size_t)1<<20;
  ushort* Wqb  = (ushort*)(ws +  0*MB);
  ushort* Wkb  = (ushort*)(ws +  2*MB);
  ushort* Wvb  = (ushort*)(ws +  4*MB);
  ushort* Wzb  = (ushort*)(ws +  6*MB);
  ushort* Wob  = (ushort*)(ws +  8*MB);
  ushort* Wgb  = (ushort*)(ws + 10*MB);
  ushort* gdwb = (ushort*)(ws + 12*MB);
  ushort* guwb = (ushort*)(ws + 12*MB + (512<<10));
  ushort* f1wb = (ushort*)(ws + 13*MB);
  ushort* f2wb = (ushort*)(ws + 21*MB);
  ushort* xn   = (ushort*)(ws + 29*MB);
  ushort* qb   = (ushort*)(ws + 37*MB);
  ushort* kb   = (ushort*)(ws + 45*MB);
  ushort* vb   = (ushort*)(ws + 53*MB);
  ushort* zb16 = (ushort*)(ws + 61*MB);
  ushort* ff1  = (ushort*)(ws + 37*MB);   // aliases qb..zb16 (dead by then)
  ushort* t1   = (ushort*)(ws + 69*MB);
  ushort* hseq = (ushort*)(ws + 70*MB);
  ushort* aob  = (ushort*)(ws + 78*MB);
  float*  zb32 = (float*) (ws + 86*MB);
  float*  yf   = (float*) (ws + 86*MB);   // aliases zb32 (dead after scan)
  float*  gm32 = (float*) (ws +102*MB);
  ushort* hst  = (ushort*)(ws +118*MB);
  unsigned int* flags = (unsigned int*)(ws + 118*MB + 65536);
  ushort* yn = xn;

  // 0. cast weights fp32 -> bf16
  cast_k<<<1024, 256, 0, stream>>>(Wq,  Wqb, 1048576);
  cast_k<<<1024, 256, 0, stream>>>(Wk,  Wkb, 1048576);
  cast_k<<<1024, 256, 0, stream>>>(Wv,  Wvb, 1048576);
  cast_k<<<1024, 256, 0, stream>>>(Wz,  Wzb, 1048576);
  cast_k<<<1024, 256, 0, stream>>>(Wo,  Wob, 1048576);
  cast_k<<<1024, 256, 0, stream>>>(Wg_, Wgb, 1048576);
  cast_k<<< 128, 256, 0, stream>>>(gdw, gdwb, 131072);
  cast_k<<< 128, 256, 0, stream>>>(guw, guwb, 131072);
  cast_k<<<4096, 256, 0, stream>>>(f1w, f1wb, 4194304);
  cast_k<<<4096, 256, 0, stream>>>(f2w, f2wb, 4194304);
  // 1. rmsnorm(x)
  rmsnorm_k<<<4096, 256, 0, stream>>>(x, n1w, xn);
  // 2. Q/K/V/Z projections
  gemm_bt<ACT_NONE,EPI_B16 ><<<dim3(32,8), 256, 0, stream>>>(xn, Wqb, bq, 1024, 1024, qb,  nullptr, nullptr, nullptr, nullptr);
  gemm_bt<ACT_NONE,EPI_B16 ><<<dim3(32,8), 256, 0, stream>>>(xn, Wkb, bk, 1024, 1024, kb,  nullptr, nullptr, nullptr, nullptr);
  gemm_bt<ACT_NONE,EPI_B16 ><<<dim3(32,8), 256, 0, stream>>>(xn, Wvb, bv, 1024, 1024, vb,  nullptr, nullptr, nullptr, nullptr);
  gemm_bt<ACT_NONE,EPI_DUAL><<<dim3(32,8), 256, 0, stream>>>(xn, Wzb, bz, 1024, 1024, zb16, zb32,   nullptr, nullptr, nullptr);
  // 3. gamma
  gemm_bt<ACT_RELU,EPI_B16><<<dim3(32,1), 256, 0, stream>>>(zb16, gdwb, gdb, 128, 1024, t1, nullptr, nullptr, nullptr, nullptr);
  gemm_bt<ACT_SIG ,EPI_F32><<<dim3(32,8), 256, 0, stream>>>(t1, guwb, gub, 1024, 128, nullptr, gm32, nullptr, nullptr, nullptr);
  // 4. attention
  attn_k<<<dim3(16,64), 256, 0, stream>>>(qb, kb, vb, aob);
  // 5. recurrence
  (void)hipMemsetAsync(flags, 0, 4096, stream);
  scan_k<<<dim3(NBS), 256, 0, stream>>>(Wgb, bg, zb32, gm32, hseq, hst, flags);
  // 6. y = x + ao@Wo.T+bo + hseq
  gemm_bt<ACT_NONE,EPI_Y><<<dim3(32,8), 256, 0, stream>>>(aob, Wob, bo, 1024, 1024, nullptr, yf, x, hseq, nullptr);
  // 7. FFN + out
  rmsnorm_k<<<4096, 256, 0, stream>>>(yf, n2w, yn);
  gemm_bt<ACT_GELU,EPI_B16><<<dim3(32,32), 256, 0, stream>>>(yn, f1wb, f1b, 4096, 1024, ff1, nullptr, nullptr, nullptr, nullptr);
  gemm_bt<ACT_NONE,EPI_OUT><<<dim3(32,8), 256, 0, stream>>>(ff1, f2wb, f2b, 1024, 4096, nullptr, (float*)d_out, nullptr, nullptr, yf);
}

// Round 5
// 6192.162 us; speedup vs baseline: 1.3331x; 1.3331x over previous
//
#include <hip/hip_runtime.h>
#include <stdint.h>

#define DD 1024   // D
#define SS 1024   // S
#define NBS 32    // scan blocks (co-resident: 32 <= 256 CUs)

typedef __attribute__((ext_vector_type(8))) __bf16 bf16x8;
typedef __attribute__((ext_vector_type(4))) float f32x4;

union Frag { uint4 u; bf16x8 b; };

__device__ __forceinline__ float bf2f(ushort u){ union{uint32_t i; float f;} c; c.i = ((uint32_t)u)<<16; return c.f; }
__device__ __forceinline__ float bflo(uint32_t p){ union{uint32_t i; float f;} c; c.i = p<<16; return c.f; }
__device__ __forceinline__ float bfhi(uint32_t p){ union{uint32_t i; float f;} c; c.i = p & 0xffff0000u; return c.f; }
__device__ __forceinline__ ushort f2bf(float f){
  union{float f; uint32_t u;} c; c.f = f;
  uint32_t u = c.u;
  return (ushort)((u + 0x7fffu + ((u>>16)&1u)) >> 16);   // RNE
}

// ------------------------------------------------------------------- cast ---
__global__ __launch_bounds__(256) void cast_k(const float* __restrict__ s,
    ushort* __restrict__ d, int n)
{
  int i = (blockIdx.x*256 + threadIdx.x)*4;
  if (i >= n) return;
  float4 v = *(const float4*)(s+i);
  ushort4 o; o.x=f2bf(v.x); o.y=f2bf(v.y); o.z=f2bf(v.z); o.w=f2bf(v.w);
  *(ushort4*)(d+i) = o;
}

// ---------------------------------------------------------------- rmsnorm ---
__global__ __launch_bounds__(256) void rmsnorm_k(const float* __restrict__ X,
    const float* __restrict__ w, ushort* __restrict__ out)
{
  const int row = blockIdx.x, t = threadIdx.x;
  const float* x = X + (size_t)row*DD;
  float xs[4]; float s = 0.f;
  #pragma unroll
  for (int i=0;i<4;i++){ float v = x[t + i*256]; xs[i]=v; s += v*v; }
  #pragma unroll
  for (int off=32; off>0; off>>=1) s += __shfl_xor(s, off, 64);
  __shared__ float sred[4];
  if ((t&63)==0) sred[t>>6] = s;
  __syncthreads();
  s = sred[0]+sred[1]+sred[2]+sred[3];
  float inv = 1.f/(sqrtf(s)*0.03125f + 1e-6f);   // /sqrt(1024), + eps
  #pragma unroll
  for (int i=0;i<4;i++){
    int c2 = t + i*256;
    out[(size_t)row*DD + c2] = f2bf(xs[i]*inv*w[c2]);
  }
}

// ---------------------------------------------------------- MFMA GEMM (BT) --
enum { ACT_NONE=0, ACT_RELU=1, ACT_SIG=2, ACT_GELU=3 };
enum { EPI_B16=0, EPI_DUAL=1, EPI_F32=2, EPI_Y=3, EPI_OUT=4 };

template<int ACT, int EPI>
__global__ __launch_bounds__(256) void gemm_bt(
    const ushort* __restrict__ A, const ushort* __restrict__ W,
    const float* __restrict__ bias, int N, int K,
    ushort* __restrict__ Ob, float* __restrict__ Of,
    const float* __restrict__ X32, const ushort* __restrict__ H16,
    const float* __restrict__ Yf)
{
  __shared__ __align__(16) ushort At[128*32];
  __shared__ __align__(16) ushort Wt[128*32];
  const int tid = threadIdx.x;
  const int wave = tid >> 6, lane = tid & 63;
  const int quad = lane >> 4, l16 = lane & 15;
  const int wr = wave >> 1, wc = wave & 1;
  const int m0 = blockIdx.x * 128, n0 = blockIdx.y * 128;

  f32x4 acc[4][4];
  const f32x4 vz = {0.f,0.f,0.f,0.f};
  #pragma unroll
  for (int i=0;i<4;i++)
    #pragma unroll
    for (int j=0;j<4;j++) acc[i][j] = vz;

  const ushort* gA = A + (size_t)(m0 + wave*32 + (lane>>2))*K + (lane&3)*8;
  const ushort* gW = W + (size_t)(n0 + wave*32 + (lane>>2))*K + (lane&3)*8;
  ushort* lA = At + wave*1024 + lane*8;
  ushort* lW = Wt + wave*1024 + lane*8;

  for (int ko = 0; ko < K; ko += 32) {
    uint4 va  = *(const uint4*)(gA + ko);
    uint4 va2 = *(const uint4*)(gA + ko + (size_t)16*K);
    uint4 vw  = *(const uint4*)(gW + ko);
    uint4 vw2 = *(const uint4*)(gW + ko + (size_t)16*K);
    __syncthreads();
    *(uint4*)lA          = va;
    *(uint4*)(lA + 512)  = va2;
    *(uint4*)lW          = vw;
    *(uint4*)(lW + 512)  = vw2;
    __syncthreads();
    Frag af[4], bfr[4];
    #pragma unroll
    for (int mi=0;mi<4;mi++)
      af[mi].u = *(const uint4*)&At[(wr*64 + mi*16 + l16)*32 + quad*8];
    #pragma unroll
    for (int ni=0;ni<4;ni++)
      bfr[ni].u = *(const uint4*)&Wt[(wc*64 + ni*16 + l16)*32 + quad*8];
    #pragma unroll
    for (int mi=0;mi<4;mi++)
      #pragma unroll
      for (int ni=0;ni<4;ni++)
        acc[mi][ni] = __builtin_amdgcn_mfma_f32_16x16x32_bf16(af[mi].b, bfr[ni].b, acc[mi][ni], 0,0,0);
  }

  float bia[4];
  #pragma unroll
  for (int ni=0;ni<4;ni++) bia[ni] = bias[n0 + wc*64 + ni*16 + l16];
  #pragma unroll
  for (int mi=0;mi<4;mi++) {
    const int row0 = m0 + wr*64 + mi*16 + quad*4;
    #pragma unroll
    for (int ni=0;ni<4;ni++) {
      const int col = n0 + wc*64 + ni*16 + l16;
      #pragma unroll
      for (int r=0;r<4;r++) {
        float vx = acc[mi][ni][r] + bia[ni];
        if (ACT == ACT_RELU) vx = fmaxf(vx, 0.f);
        else if (ACT == ACT_SIG) {
          vx = 1.f/(1.f+__expf(-vx));
          vx = fminf(fmaxf(vx, 1e-6f), 1.f-1e-6f);
        } else if (ACT == ACT_GELU) {
          float ci = 0.7978845608028654f*(vx + 0.044715f*vx*vx*vx);
          float th = 1.f - 2.f/(1.f + __expf(2.f*ci));
          vx = 0.5f*vx*(1.f+th);
        }
        size_t idx = (size_t)(row0 + r)*N + col;
        if (EPI == EPI_B16)      Ob[idx] = f2bf(vx);
        else if (EPI == EPI_DUAL){ Ob[idx] = f2bf(vx); Of[idx] = vx; }
        else if (EPI == EPI_F32)  Of[idx] = vx;
        else if (EPI == EPI_Y)    Of[idx] = vx + X32[idx] + bf2f(H16[idx]);
        else                      Of[idx] = vx + Yf[idx];
      }
    }
  }
}

// ------------------------------------------------------------- attention ----
__global__ __launch_bounds__(256) void attn_k(const ushort* __restrict__ q,
  const ushort* __restrict__ k, const ushort* __restrict__ v, ushort* __restrict__ ao)
{
  __shared__ __align__(16) ushort Ks[64*64];
  __shared__ __align__(16) ushort Vs[64*64];
  __shared__ float Ps[64*65];
  const int qt = blockIdx.x, bh = blockIdx.y;
  const int b = bh >> 4, h = bh & 15;
  const int t = threadIdx.x, r = t >> 2, seg = t & 3;
  const ushort* qrow = q + ((size_t)(b*SS + qt*64 + r))*DD + h*64;
  float qr[64];
  #pragma unroll
  for (int i=0;i<64;i+=8){
    uint4 u = *(const uint4*)(qrow + i);
    qr[i+0]=bflo(u.x); qr[i+1]=bfhi(u.x); qr[i+2]=bflo(u.y); qr[i+3]=bfhi(u.y);
    qr[i+4]=bflo(u.z); qr[i+5]=bfhi(u.z); qr[i+6]=bflo(u.w); qr[i+7]=bfhi(u.w);
  }
  float o[16];
  #pragma unroll
  for (int i=0;i<16;i++) o[i]=0.f;
  float mrun = -1e30f, lrun = 0.f;
  const int jrow = t >> 3, jch = t & 7;
  for (int kt=0; kt<16; kt++) {
    __syncthreads();
    const ushort* kg = k + ((size_t)(b*SS + kt*64))*DD + h*64;
    const ushort* vg = v + ((size_t)(b*SS + kt*64))*DD + h*64;
    #pragma unroll
    for (int part=0; part<2; part++){
      int j = jrow + part*32;
      *(uint4*)&Ks[j*64 + jch*8] = *(const uint4*)(kg + (size_t)j*DD + jch*8);
      *(uint4*)&Vs[j*64 + jch*8] = *(const uint4*)(vg + (size_t)j*DD + jch*8);
    }
    __syncthreads();
    float sc[16];
    #pragma unroll
    for (int jj=0;jj<16;jj++){
      int j = seg*16 + jj;
      float s_ = 0.f;
      #pragma unroll
      for (int i=0;i<64;i+=8){
        uint4 u = *(const uint4*)&Ks[j*64+i];
        s_ = fmaf(qr[i+0], bflo(u.x), s_); s_ = fmaf(qr[i+1], bfhi(u.x), s_);
        s_ = fmaf(qr[i+2], bflo(u.y), s_); s_ = fmaf(qr[i+3], bfhi(u.y), s_);
        s_ = fmaf(qr[i+4], bflo(u.z), s_); s_ = fmaf(qr[i+5], bfhi(u.z), s_);
        s_ = fmaf(qr[i+6], bflo(u.w), s_); s_ = fmaf(qr[i+7], bfhi(u.w), s_);
      }
      sc[jj] = s_ * 0.125f;
    }
    float mx = sc[0];
    #pragma unroll
    for (int jj=1;jj<16;jj++) mx = fmaxf(mx, sc[jj]);
    mx = fmaxf(mx, __shfl_xor(mx, 1, 64));
    mx = fmaxf(mx, __shfl_xor(mx, 2, 64));
    float mnew = fmaxf(mrun, mx);
    float psum = 0.f;
    #pragma unroll
    for (int jj=0;jj<16;jj++){
      float p = __expf(sc[jj]-mnew);
      Ps[r*65 + seg*16 + jj] = p;
      psum += p;
    }
    psum += __shfl_xor(psum, 1, 64);
    psum += __shfl_xor(psum, 2, 64);
    float alpha = __expf(mrun - mnew);
    lrun = lrun*alpha + psum;
    mrun = mnew;
    #pragma unroll
    for (int i=0;i<16;i++) o[i] *= alpha;
    __syncthreads();
    #pragma unroll 4
    for (int j=0;j<64;j++){
      float pj = Ps[r*65 + j];
      uint4 u0 = *(const uint4*)&Vs[j*64 + seg*16];
      uint4 u1 = *(const uint4*)&Vs[j*64 + seg*16 + 8];
      o[ 0]=fmaf(pj,bflo(u0.x),o[ 0]); o[ 1]=fmaf(pj,bfhi(u0.x),o[ 1]);
      o[ 2]=fmaf(pj,bflo(u0.y),o[ 2]); o[ 3]=fmaf(pj,bfhi(u0.y),o[ 3]);
      o[ 4]=fmaf(pj,bflo(u0.z),o[ 4]); o[ 5]=fmaf(pj,bfhi(u0.z),o[ 5]);
      o[ 6]=fmaf(pj,bflo(u0.w),o[ 6]); o[ 7]=fmaf(pj,bfhi(u0.w),o[ 7]);
      o[ 8]=fmaf(pj,bflo(u1.x),o[ 8]); o[ 9]=fmaf(pj,bfhi(u1.x),o[ 9]);
      o[10]=fmaf(pj,bflo(u1.y),o[10]); o[11]=fmaf(pj,bfhi(u1.y),o[11]);
      o[12]=fmaf(pj,bflo(u1.z),o[12]); o[13]=fmaf(pj,bfhi(u1.z),o[13]);
      o[14]=fmaf(pj,bflo(u1.w),o[14]); o[15]=fmaf(pj,bfhi(u1.w),o[15]);
    }
  }
  float invl = 1.f/lrun;
  ushort* orow = ao + ((size_t)(b*SS + qt*64 + r))*DD + h*64 + seg*16;
  #pragma unroll
  for (int i=0;i<16;i++) orow[i] = f2bf(o[i]*invl);
}

// ----------------------------------------------------------------- scan -----
// h_t = z_t * sigmoid(Wg h_{t-1} + bg) + gamma_t * h_{t-1}. Round-5 protocol:
//  - flag per block (own 64B line), RELAXED store after __syncthreads
//    (barrier drains vmcnt -> h atomic stores acked at coherence point first)
//  - RELAXED polls by wave 0 only, ballot across the 32 flags
//  - staging: 32-bit relaxed agent atomic loads (plain sc1 loads, NOT RMWs --
//    the 64-bit variant lowered to RMWs: R4's +390MB WRITE_SIZE)
//  - no acquire/release/threadfence anywhere in the loop: MALL is the single
//    serialization point; flag observed => h stores already acked there
__global__ __launch_bounds__(256) void scan_k(
    const ushort* __restrict__ Wgb, const float* __restrict__ bg,
    const float* __restrict__ z32, const float* __restrict__ gm32,
    ushort* __restrict__ hseq, ushort* __restrict__ hstate, // 2 x [4][1024] bf16
    unsigned int* __restrict__ flags)                        // 32 x 16 dwords
{
  const int blk = blockIdx.x, t = threadIdx.x;
  const int wave = t>>6, lane = t&63, quad = lane>>4, c = lane&15;
  const int mt = wave & 1, kh = wave >> 1;
  const int nbase = blk*32 + mt*16;
  const bool epi = (kh == 0) && (c < 4);
  const int n0w = nbase + quad*4;
  Frag a[16];                                   // Wg A-frags, loop-invariant
  {
    const ushort* wrow = Wgb + (size_t)(nbase + c)*DD + kh*512 + quad*8;
    #pragma unroll
    for (int kt=0;kt<16;kt++) a[kt].u = *(const uint4*)(wrow + kt*32);
  }
  float bgv[4];
  #pragma unroll
  for (int r=0;r<4;r++) bgv[r] = bg[nbase + quad*4 + r];
  __shared__ __align__(16) ushort Hs[4096];     // staged h_{t-1}
  __shared__ float redbuf[2][64][5];

  for (int st=0; st<SS; st++) {
    // prefetch z/gamma for this step (independent of the barrier)
    float zr[4], gr[4];
    if (epi) {
      float4 z4 = *(const float4*)(z32  + ((size_t)c*SS + st)*DD + n0w);
      float4 g4 = *(const float4*)(gm32 + ((size_t)c*SS + st)*DD + n0w);
      zr[0]=z4.x; zr[1]=z4.y; zr[2]=z4.z; zr[3]=z4.w;
      gr[0]=g4.x; gr[1]=g4.y; gr[2]=g4.z; gr[3]=g4.w;
    }
    if (st > 0) {
      if (t < 64) {                      // wave 0 polls all 32 flags at once
        const unsigned int* fp = flags + ((t & 31) << 4);
        for (;;) {
          unsigned v = __hip_atomic_load(fp, __ATOMIC_RELAXED, __HIP_MEMORY_SCOPE_AGENT);
          if (__ballot(v < (unsigned)st) == 0ull) break;
          __builtin_amdgcn_s_sleep(2);
        }
      }
      __syncthreads();
      // stage h_{t-1} into LDS via 32-bit agent atomic loads (L1-bypass)
      const uint32_t* hrd = (const uint32_t*)(hstate + ((st+1)&1)*4096);
      uint32_t* hsd = (uint32_t*)Hs;
      #pragma unroll
      for (int i=0;i<8;i++)
        hsd[t + i*256] = __hip_atomic_load(hrd + t + i*256, __ATOMIC_RELAXED, __HIP_MEMORY_SCOPE_AGENT);
      __syncthreads();
    }
    f32x4 acc = {0.f,0.f,0.f,0.f};
    if (st > 0) {
      f32x4 acc1 = {0.f,0.f,0.f,0.f};
      const uint4 z4 = make_uint4(0u,0u,0u,0u);
      #pragma unroll
      for (int kt=0;kt<16;kt+=2) {
        Frag b0, b1;
        b0.u = (c<4) ? *(const uint4*)&Hs[c*1024 + kh*512 + (kt  )*32 + quad*8] : z4;
        b1.u = (c<4) ? *(const uint4*)&Hs[c*1024 + kh*512 + (kt+1)*32 + quad*8] : z4;
        acc  = __builtin_amdgcn_mfma_f32_16x16x32_bf16(a[kt  ].b, b0.b, acc,  0,0,0);
        acc1 = __builtin_amdgcn_mfma_f32_16x16x32_bf16(a[kt+1].b, b1.b, acc1, 0,0,0);
      }
      #pragma unroll
      for (int r=0;r<4;r++) acc[r] += acc1[r];
    }
    if (kh == 1) {
      #pragma unroll
      for (int r=0;r<4;r++) redbuf[mt][lane][r] = acc[r];
    }
    __syncthreads();
    if (epi) {
      ushort hb[4];
      #pragma unroll
      for (int r=0;r<4;r++) {
        float g = acc[r] + redbuf[mt][lane][r] + bgv[r];
        g = 1.f/(1.f+__expf(-g));
        float hp = (st>0) ? bf2f(Hs[c*1024 + n0w + r]) : 0.f;
        hb[r] = f2bf(zr[r]*g + gr[r]*hp);
      }
      uint32_t p0 = (uint32_t)hb[0] | ((uint32_t)hb[1]<<16);
      uint32_t p1 = (uint32_t)hb[2] | ((uint32_t)hb[3]<<16);
      uint32_t* hwd = (uint32_t*)(hstate + (st&1)*4096);
      int di = (c*1024 + n0w) >> 1;
      __hip_atomic_store(hwd + di,     p0, __ATOMIC_RELAXED, __HIP_MEMORY_SCOPE_AGENT);
      __hip_atomic_store(hwd + di + 1, p1, __ATOMIC_RELAXED, __HIP_MEMORY_SCOPE_AGENT);
      uint32_t* sq = (uint32_t*)(hseq + ((size_t)c*SS + st)*DD + n0w);
      sq[0] = p0; sq[1] = p1;            // cached store: stays in L2
    }
    __syncthreads();                     // drains vmcnt: h stores acked at MALL
    if (t == 0)
      __hip_atomic_store(flags + (blk<<4), (unsigned)(st+1),
                         __ATOMIC_RELAXED, __HIP_MEMORY_SCOPE_AGENT);
  }
}

// --------------------------------------------------------------- launch -----
extern "C" void kernel_launch(void* const* d_in, const int* in_sizes, int n_in,
                              void* d_out, int out_size, void* d_ws, size_t ws_size,
                              hipStream_t stream)
{
  const float* x   = (const float*)d_in[0];
  const float* n1w = (const float*)d_in[1];
  const float* Wq  = (const float*)d_in[2];
  const float* bq  = (const float*)d_in[3];
  const float* Wk  = (const float*)d_in[4];
  const float* bk  = (const float*)d_in[5];
  const float* Wv  = (const float*)d_in[6];
  const float* bv  = (const float*)d_in[7];
  const float* Wz  = (const float*)d_in[8];
  const float* bz  = (const float*)d_in[9];
  const float* Wg_ = (const float*)d_in[10];
  const float* bg  = (const float*)d_in[11];
  const float* gdw = (const float*)d_in[12];
  const float* gdb = (const float*)d_in[13];
  const float* guw = (const float*)d_in[14];
  const float* gub = (const float*)d_in[15];
  const float* Wo  = (const float*)d_in[16];
  const float* bo  = (const float*)d_in[17];
  const float* n2w = (const float*)d_in[18];
  const float* f1w = (const float*)d_in[19];
  const float* f1b = (const float*)d_in[20];
  const float* f2w = (const float*)d_in[21];
  const float* f2b = (const float*)d_in[22];

  char* ws = (char*)d_ws;
  const size_t MB = (size_t)1<<20;
  ushort* Wqb  = (ushort*)(ws +  0*MB);
  ushort* Wkb  = (ushort*)(ws +  2*MB);
  ushort* Wvb  = (ushort*)(ws +  4*MB);
  ushort* Wzb  = (ushort*)(ws +  6*MB);
  ushort* Wob  = (ushort*)(ws +  8*MB);
  ushort* Wgb  = (ushort*)(ws + 10*MB);
  ushort* gdwb = (ushort*)(ws + 12*MB);
  ushort* guwb = (ushort*)(ws + 12*MB + (512<<10));
  ushort* f1wb = (ushort*)(ws + 13*MB);
  ushort* f2wb = (ushort*)(ws + 21*MB);
  ushort* xn   = (ushort*)(ws + 29*MB);
  ushort* qb   = (ushort*)(ws + 37*MB);
  ushort* kb   = (ushort*)(ws + 45*MB);
  ushort* vb   = (ushort*)(ws + 53*MB);
  ushort* zb16 = (ushort*)(ws + 61*MB);
  ushort* ff1  = (ushort*)(ws + 37*MB);   // aliases qb..zb16 (dead by then)
  ushort* t1   = (ushort*)(ws + 69*MB);
  ushort* hseq = (ushort*)(ws + 70*MB);
  ushort* aob  = (ushort*)(ws + 78*MB);
  float*  zb32 = (float*) (ws + 86*MB);
  float*  yf   = (float*) (ws + 86*MB);   // aliases zb32 (dead after scan)
  float*  gm32 = (float*) (ws +102*MB);
  ushort* hst  = (ushort*)(ws +118*MB);
  unsigned int* flags = (unsigned int*)(ws + 118*MB + 65536);
  ushort* yn = xn;

  // 0. cast weights fp32 -> bf16
  cast_k<<<1024, 256, 0, stream>>>(Wq,  Wqb, 1048576);
  cast_k<<<1024, 256, 0, stream>>>(Wk,  Wkb, 1048576);
  cast_k<<<1024, 256, 0, stream>>>(Wv,  Wvb, 1048576);
  cast_k<<<1024, 256, 0, stream>>>(Wz,  Wzb, 1048576);
  cast_k<<<1024, 256, 0, stream>>>(Wo,  Wob, 1048576);
  cast_k<<<1024, 256, 0, stream>>>(Wg_, Wgb, 1048576);
  cast_k<<< 128, 256, 0, stream>>>(gdw, gdwb, 131072);
  cast_k<<< 128, 256, 0, stream>>>(guw, guwb, 131072);
  cast_k<<<4096, 256, 0, stream>>>(f1w, f1wb, 4194304);
  cast_k<<<4096, 256, 0, stream>>>(f2w, f2wb, 4194304);
  // 1. rmsnorm(x)
  rmsnorm_k<<<4096, 256, 0, stream>>>(x, n1w, xn);
  // 2. Q/K/V/Z projections
  gemm_bt<ACT_NONE,EPI_B16 ><<<dim3(32,8), 256, 0, stream>>>(xn, Wqb, bq, 1024, 1024, qb,  nullptr, nullptr, nullptr, nullptr);
  gemm_bt<ACT_NONE,EPI_B16 ><<<dim3(32,8), 256, 0, stream>>>(xn, Wkb, bk, 1024, 1024, kb,  nullptr, nullptr, nullptr, nullptr);
  gemm_bt<ACT_NONE,EPI_B16 ><<<dim3(32,8), 256, 0, stream>>>(xn, Wvb, bv, 1024, 1024, vb,  nullptr, nullptr, nullptr, nullptr);
  gemm_bt<ACT_NONE,EPI_DUAL><<<dim3(32,8), 256, 0, stream>>>(xn, Wzb, bz, 1024, 1024, zb16, zb32,   nullptr, nullptr, nullptr);
  // 3. gamma
  gemm_bt<ACT_RELU,EPI_B16><<<dim3(32,1), 256, 0, stream>>>(zb16, gdwb, gdb, 128, 1024, t1, nullptr, nullptr, nullptr, nullptr);
  gemm_bt<ACT_SIG ,EPI_F32><<<dim3(32,8), 256, 0, stream>>>(t1, guwb, gub, 1024, 128, nullptr, gm32, nullptr, nullptr, nullptr);
  // 4. attention
  attn_k<<<dim3(16,64), 256, 0, stream>>>(qb, kb, vb, aob);
  // 5. recurrence
  (void)hipMemsetAsync(flags, 0, 4096, stream);
  scan_k<<<dim3(NBS), 256, 0, stream>>>(Wgb, bg, zb32, gm32, hseq, hst, flags);
  // 6. y = x + ao@Wo.T+bo + hseq
  gemm_bt<ACT_NONE,EPI_Y><<<dim3(32,8), 256, 0, stream>>>(aob, Wob, bo, 1024, 1024, nullptr, yf, x, hseq, nullptr);
  // 7. FFN + out
  rmsnorm_k<<<4096, 256, 0, stream>>>(yf, n2w, yn);
  gemm_bt<ACT_GELU,EPI_B16><<<dim3(32,32), 256, 0, stream>>>(yn, f1wb, f1b, 4096, 1024, ff1, nullptr, nullptr, nullptr, nullptr);
  gemm_bt<ACT_NONE,EPI_OUT><<<dim3(32,8), 256, 0, stream>>>(ff1, f2wb, f2b, 1024, 4096, nullptr, (float*)d_out, nullptr, nullptr, yf);
}

// Round 8
// 4943.835 us; speedup vs baseline: 1.6697x; 1.2525x over previous
//
#include <hip/hip_runtime.h>
#include <stdint.h>

#define DD 1024   // D
#define SS 1024   // S
#define NBS 32    // scan blocks (co-resident: 32 <= 256 CUs)

typedef __attribute__((ext_vector_type(8))) __bf16 bf16x8;
typedef __attribute__((ext_vector_type(4))) float f32x4;

union Frag { uint4 u; bf16x8 b; };

__device__ __forceinline__ float bf2f(ushort u){ union{uint32_t i; float f;} c; c.i = ((uint32_t)u)<<16; return c.f; }
__device__ __forceinline__ float bflo(uint32_t p){ union{uint32_t i; float f;} c; c.i = p<<16; return c.f; }
__device__ __forceinline__ float bfhi(uint32_t p){ union{uint32_t i; float f;} c; c.i = p & 0xffff0000u; return c.f; }
__device__ __forceinline__ ushort f2bf(float f){
  union{float f; uint32_t u;} c; c.f = f;
  uint32_t u = c.u;
  return (ushort)((u + 0x7fffu + ((u>>16)&1u)) >> 16);   // RNE
}

// ------------------------------------------------------------------- cast ---
__global__ __launch_bounds__(256) void cast_k(const float* __restrict__ s,
    ushort* __restrict__ d, int n)
{
  int i = (blockIdx.x*256 + threadIdx.x)*4;
  if (i >= n) return;
  float4 v = *(const float4*)(s+i);
  ushort4 o; o.x=f2bf(v.x); o.y=f2bf(v.y); o.z=f2bf(v.z); o.w=f2bf(v.w);
  *(ushort4*)(d+i) = o;
}

// ---------------------------------------------------------------- rmsnorm ---
__global__ __launch_bounds__(256) void rmsnorm_k(const float* __restrict__ X,
    const float* __restrict__ w, ushort* __restrict__ out)
{
  const int row = blockIdx.x, t = threadIdx.x;
  const float* x = X + (size_t)row*DD;
  float xs[4]; float s = 0.f;
  #pragma unroll
  for (int i=0;i<4;i++){ float v = x[t + i*256]; xs[i]=v; s += v*v; }
  #pragma unroll
  for (int off=32; off>0; off>>=1) s += __shfl_xor(s, off, 64);
  __shared__ float sred[4];
  if ((t&63)==0) sred[t>>6] = s;
  __syncthreads();
  s = sred[0]+sred[1]+sred[2]+sred[3];
  float inv = 1.f/(sqrtf(s)*0.03125f + 1e-6f);   // /sqrt(1024), + eps
  #pragma unroll
  for (int i=0;i<4;i++){
    int c2 = t + i*256;
    out[(size_t)row*DD + c2] = f2bf(xs[i]*inv*w[c2]);
  }
}

// ---------------------------------------------------------- MFMA GEMM (BT) --
enum { ACT_NONE=0, ACT_RELU=1, ACT_SIG=2, ACT_GELU=3 };
enum { EPI_B16=0, EPI_DUAL=1, EPI_F32=2, EPI_Y=3, EPI_OUT=4 };

template<int ACT, int EPI>
__global__ __launch_bounds__(256) void gemm_bt(
    const ushort* __restrict__ A, const ushort* __restrict__ W,
    const float* __restrict__ bias, int N, int K,
    ushort* __restrict__ Ob, float* __restrict__ Of,
    const float* __restrict__ X32, const ushort* __restrict__ H16,
    const float* __restrict__ Yf)
{
  __shared__ __align__(16) ushort At[128*32];
  __shared__ __align__(16) ushort Wt[128*32];
  const int tid = threadIdx.x;
  const int wave = tid >> 6, lane = tid & 63;
  const int quad = lane >> 4, l16 = lane & 15;
  const int wr = wave >> 1, wc = wave & 1;
  const int m0 = blockIdx.x * 128, n0 = blockIdx.y * 128;

  f32x4 acc[4][4];
  const f32x4 vz = {0.f,0.f,0.f,0.f};
  #pragma unroll
  for (int i=0;i<4;i++)
    #pragma unroll
    for (int j=0;j<4;j++) acc[i][j] = vz;

  const ushort* gA = A + (size_t)(m0 + wave*32 + (lane>>2))*K + (lane&3)*8;
  const ushort* gW = W + (size_t)(n0 + wave*32 + (lane>>2))*K + (lane&3)*8;
  ushort* lA = At + wave*1024 + lane*8;
  ushort* lW = Wt + wave*1024 + lane*8;

  for (int ko = 0; ko < K; ko += 32) {
    uint4 va  = *(const uint4*)(gA + ko);
    uint4 va2 = *(const uint4*)(gA + ko + (size_t)16*K);
    uint4 vw  = *(const uint4*)(gW + ko);
    uint4 vw2 = *(const uint4*)(gW + ko + (size_t)16*K);
    __syncthreads();
    *(uint4*)lA          = va;
    *(uint4*)(lA + 512)  = va2;
    *(uint4*)lW          = vw;
    *(uint4*)(lW + 512)  = vw2;
    __syncthreads();
    Frag af[4], bfr[4];
    #pragma unroll
    for (int mi=0;mi<4;mi++)
      af[mi].u = *(const uint4*)&At[(wr*64 + mi*16 + l16)*32 + quad*8];
    #pragma unroll
    for (int ni=0;ni<4;ni++)
      bfr[ni].u = *(const uint4*)&Wt[(wc*64 + ni*16 + l16)*32 + quad*8];
    #pragma unroll
    for (int mi=0;mi<4;mi++)
      #pragma unroll
      for (int ni=0;ni<4;ni++)
        acc[mi][ni] = __builtin_amdgcn_mfma_f32_16x16x32_bf16(af[mi].b, bfr[ni].b, acc[mi][ni], 0,0,0);
  }

  float bia[4];
  #pragma unroll
  for (int ni=0;ni<4;ni++) bia[ni] = bias[n0 + wc*64 + ni*16 + l16];
  #pragma unroll
  for (int mi=0;mi<4;mi++) {
    const int row0 = m0 + wr*64 + mi*16 + quad*4;
    #pragma unroll
    for (int ni=0;ni<4;ni++) {
      const int col = n0 + wc*64 + ni*16 + l16;
      #pragma unroll
      for (int r=0;r<4;r++) {
        float vx = acc[mi][ni][r] + bia[ni];
        if (ACT == ACT_RELU) vx = fmaxf(vx, 0.f);
        else if (ACT == ACT_SIG) {
          vx = 1.f/(1.f+__expf(-vx));
          vx = fminf(fmaxf(vx, 1e-6f), 1.f-1e-6f);
        } else if (ACT == ACT_GELU) {
          float ci = 0.7978845608028654f*(vx + 0.044715f*vx*vx*vx);
          float th = 1.f - 2.f/(1.f + __expf(2.f*ci));
          vx = 0.5f*vx*(1.f+th);
        }
        size_t idx = (size_t)(row0 + r)*N + col;
        if (EPI == EPI_B16)      Ob[idx] = f2bf(vx);
        else if (EPI == EPI_DUAL){ Ob[idx] = f2bf(vx); Of[idx] = vx; }
        else if (EPI == EPI_F32)  Of[idx] = vx;
        else if (EPI == EPI_Y)    Of[idx] = vx + X32[idx] + bf2f(H16[idx]);
        else                      Of[idx] = vx + Yf[idx];
      }
    }
  }
}

// ------------------------------------------------------------- attention ----
__global__ __launch_bounds__(256) void attn_k(const ushort* __restrict__ q,
  const ushort* __restrict__ k, const ushort* __restrict__ v, ushort* __restrict__ ao)
{
  __shared__ __align__(16) ushort Ks[64*64];
  __shared__ __align__(16) ushort Vs[64*64];
  __shared__ float Ps[64*65];
  const int qt = blockIdx.x, bh = blockIdx.y;
  const int b = bh >> 4, h = bh & 15;
  const int t = threadIdx.x, r = t >> 2, seg = t & 3;
  const ushort* qrow = q + ((size_t)(b*SS + qt*64 + r))*DD + h*64;
  float qr[64];
  #pragma unroll
  for (int i=0;i<64;i+=8){
    uint4 u = *(const uint4*)(qrow + i);
    qr[i+0]=bflo(u.x); qr[i+1]=bfhi(u.x); qr[i+2]=bflo(u.y); qr[i+3]=bfhi(u.y);
    qr[i+4]=bflo(u.z); qr[i+5]=bfhi(u.z); qr[i+6]=bflo(u.w); qr[i+7]=bfhi(u.w);
  }
  float o[16];
  #pragma unroll
  for (int i=0;i<16;i++) o[i]=0.f;
  float mrun = -1e30f, lrun = 0.f;
  const int jrow = t >> 3, jch = t & 7;
  for (int kt=0; kt<16; kt++) {
    __syncthreads();
    const ushort* kg = k + ((size_t)(b*SS + kt*64))*DD + h*64;
    const ushort* vg = v + ((size_t)(b*SS + kt*64))*DD + h*64;
    #pragma unroll
    for (int part=0; part<2; part++){
      int j = jrow + part*32;
      *(uint4*)&Ks[j*64 + jch*8] = *(const uint4*)(kg + (size_t)j*DD + jch*8);
      *(uint4*)&Vs[j*64 + jch*8] = *(const uint4*)(vg + (size_t)j*DD + jch*8);
    }
    __syncthreads();
    float sc[16];
    #pragma unroll
    for (int jj=0;jj<16;jj++){
      int j = seg*16 + jj;
      float s_ = 0.f;
      #pragma unroll
      for (int i=0;i<64;i+=8){
        uint4 u = *(const uint4*)&Ks[j*64+i];
        s_ = fmaf(qr[i+0], bflo(u.x), s_); s_ = fmaf(qr[i+1], bfhi(u.x), s_);
        s_ = fmaf(qr[i+2], bflo(u.y), s_); s_ = fmaf(qr[i+3], bfhi(u.y), s_);
        s_ = fmaf(qr[i+4], bflo(u.z), s_); s_ = fmaf(qr[i+5], bfhi(u.z), s_);
        s_ = fmaf(qr[i+6], bflo(u.w), s_); s_ = fmaf(qr[i+7], bfhi(u.w), s_);
      }
      sc[jj] = s_ * 0.125f;
    }
    float mx = sc[0];
    #pragma unroll
    for (int jj=1;jj<16;jj++) mx = fmaxf(mx, sc[jj]);
    mx = fmaxf(mx, __shfl_xor(mx, 1, 64));
    mx = fmaxf(mx, __shfl_xor(mx, 2, 64));
    float mnew = fmaxf(mrun, mx);
    float psum = 0.f;
    #pragma unroll
    for (int jj=0;jj<16;jj++){
      float p = __expf(sc[jj]-mnew);
      Ps[r*65 + seg*16 + jj] = p;
      psum += p;
    }
    psum += __shfl_xor(psum, 1, 64);
    psum += __shfl_xor(psum, 2, 64);
    float alpha = __expf(mrun - mnew);
    lrun = lrun*alpha + psum;
    mrun = mnew;
    #pragma unroll
    for (int i=0;i<16;i++) o[i] *= alpha;
    __syncthreads();
    #pragma unroll 4
    for (int j=0;j<64;j++){
      float pj = Ps[r*65 + j];
      uint4 u0 = *(const uint4*)&Vs[j*64 + seg*16];
      uint4 u1 = *(const uint4*)&Vs[j*64 + seg*16 + 8];
      o[ 0]=fmaf(pj,bflo(u0.x),o[ 0]); o[ 1]=fmaf(pj,bfhi(u0.x),o[ 1]);
      o[ 2]=fmaf(pj,bflo(u0.y),o[ 2]); o[ 3]=fmaf(pj,bfhi(u0.y),o[ 3]);
      o[ 4]=fmaf(pj,bflo(u0.z),o[ 4]); o[ 5]=fmaf(pj,bfhi(u0.z),o[ 5]);
      o[ 6]=fmaf(pj,bflo(u0.w),o[ 6]); o[ 7]=fmaf(pj,bfhi(u0.w),o[ 7]);
      o[ 8]=fmaf(pj,bflo(u1.x),o[ 8]); o[ 9]=fmaf(pj,bfhi(u1.x),o[ 9]);
      o[10]=fmaf(pj,bflo(u1.y),o[10]); o[11]=fmaf(pj,bfhi(u1.y),o[11]);
      o[12]=fmaf(pj,bflo(u1.z),o[12]); o[13]=fmaf(pj,bfhi(u1.z),o[13]);
      o[14]=fmaf(pj,bflo(u1.w),o[14]); o[15]=fmaf(pj,bfhi(u1.w),o[15]);
    }
  }
  float invl = 1.f/lrun;
  ushort* orow = ao + ((size_t)(b*SS + qt*64 + r))*DD + h*64 + seg*16;
  #pragma unroll
  for (int i=0;i<16;i++) orow[i] = f2bf(o[i]*invl);
}

// ----------------------------------------------------------------- scan -----
// h_t = z_t * sigmoid(Wg h_{t-1} + bg) + gamma_t * h_{t-1}. Round-8 = R6/R7
// DATA-IS-THE-FLAG protocol, hardened:
//  - depth-4 ring pre-set to sentinel 0xFFFFFFFF (unreachable from finite or
//    canonical-NaN bf16 pairs); consumers poll the data dwords directly
//    (relaxed agent loads): observe+stage = ONE MALL round-trip; producers
//    need no drain/flag
//  - reset: at step s each block re-sentinels its own slice of buf[(s+2)&3];
//    per-address ordering via the staging barrier's vmcnt drain (no ABA)
//  - SELF-DISARMING guard: 256 sweeps max; first trip sets gmax=0 so all later
//    steps do one sweep and proceed -> genuine stall = fast NaN fail, not hang
//  - trailing __syncthreads keeps waves 2/3 from racing into the next poll
//    before the epilogue waves issue their h stores
__global__ __launch_bounds__(256) void scan_k(
    const ushort* __restrict__ Wgb, const float* __restrict__ bg,
    const float* __restrict__ z32, const float* __restrict__ gm32,
    ushort* __restrict__ hseq, ushort* __restrict__ hstate) // 4 x [4][1024] bf16
{
  const int blk = blockIdx.x, t = threadIdx.x;
  const int wave = t>>6, lane = t&63, quad = lane>>4, c = lane&15;
  const int mt = wave & 1, kh = wave >> 1;
  const int nbase = blk*32 + mt*16;
  const bool epi = (kh == 0) && (c < 4);
  const int n0w = nbase + quad*4;
  Frag a[16];                                   // Wg A-frags, loop-invariant
  {
    const ushort* wrow = Wgb + (size_t)(nbase + c)*DD + kh*512 + quad*8;
    #pragma unroll
    for (int kt=0;kt<16;kt++) a[kt].u = *(const uint4*)(wrow + kt*32);
  }
  float bgv[4];
  #pragma unroll
  for (int r=0;r<4;r++) bgv[r] = bg[nbase + quad*4 + r];
  __shared__ __align__(16) ushort Hs[4096];     // staged h_{t-1}
  __shared__ float redbuf[2][64][5];
  const int di = (c*1024 + n0w) >> 1;           // this block's h slice (dwords)
  int gmax = 256;                                // poll budget; 0 after a trip

  for (int st=0; st<SS; st++) {
    // prefetch z/gamma for this step (independent of the poll)
    float zr[4], gr[4];
    if (epi) {
      float4 z4 = *(const float4*)(z32  + ((size_t)c*SS + st)*DD + n0w);
      float4 g4 = *(const float4*)(gm32 + ((size_t)c*SS + st)*DD + n0w);
      zr[0]=z4.x; zr[1]=z4.y; zr[2]=z4.z; zr[3]=z4.w;
      gr[0]=g4.x; gr[1]=g4.y; gr[2]=g4.z; gr[3]=g4.w;
    }
    if (st > 0) {
      // poll step st-1 data directly; valid dwords ARE the staged h
      const uint32_t* hrd = (const uint32_t*)(hstate + ((st+3)&3)*4096);
      uint32_t vals[8];
      int guard = 0;
      for (;;) {
        bool ok = true;
        #pragma unroll
        for (int i=0;i<8;i++)
          vals[i] = __hip_atomic_load(hrd + t + i*256, __ATOMIC_RELAXED, __HIP_MEMORY_SCOPE_AGENT);
        #pragma unroll
        for (int i=0;i<8;i++) ok &= (vals[i] != 0xFFFFFFFFu);
        if (ok) break;
        if (++guard > gmax) { gmax = 0; break; }  // fail fast+loud (NaN), no hang
        __builtin_amdgcn_s_sleep(2);
      }
      // re-sentinel our own slice of buf[(st-2)&3] (rewritten at st+2)
      if (epi) {
        uint32_t* rst = (uint32_t*)(hstate + ((st+2)&3)*4096);
        __hip_atomic_store(rst + di,     0xFFFFFFFFu, __ATOMIC_RELAXED, __HIP_MEMORY_SCOPE_AGENT);
        __hip_atomic_store(rst + di + 1, 0xFFFFFFFFu, __ATOMIC_RELAXED, __HIP_MEMORY_SCOPE_AGENT);
      }
      uint32_t* hsd = (uint32_t*)Hs;
      #pragma unroll
      for (int i=0;i<8;i++) hsd[t + i*256] = vals[i];
      __syncthreads();
    }
    f32x4 acc = {0.f,0.f,0.f,0.f};
    if (st > 0) {
      f32x4 acc1 = {0.f,0.f,0.f,0.f};
      const uint4 z4 = make_uint4(0u,0u,0u,0u);
      #pragma unroll
      for (int kt=0;kt<16;kt+=2) {
        Frag b0, b1;
        b0.u = (c<4) ? *(const uint4*)&Hs[c*1024 + kh*512 + (kt  )*32 + quad*8] : z4;
        b1.u = (c<4) ? *(const uint4*)&Hs[c*1024 + kh*512 + (kt+1)*32 + quad*8] : z4;
        acc  = __builtin_amdgcn_mfma_f32_16x16x32_bf16(a[kt  ].b, b0.b, acc,  0,0,0);
        acc1 = __builtin_amdgcn_mfma_f32_16x16x32_bf16(a[kt+1].b, b1.b, acc1, 0,0,0);
      }
      #pragma unroll
      for (int r=0;r<4;r++) acc[r] += acc1[r];
    }
    if (kh == 1) {
      #pragma unroll
      for (int r=0;r<4;r++) redbuf[mt][lane][r] = acc[r];
    }
    __syncthreads();
    if (epi) {
      ushort hb[4];
      #pragma unroll
      for (int r=0;r<4;r++) {
        float g = acc[r] + redbuf[mt][lane][r] + bgv[r];
        g = 1.f/(1.f+__expf(-g));
        float hp = (st>0) ? bf2f(Hs[c*1024 + n0w + r]) : 0.f;
        hb[r] = f2bf(zr[r]*g + gr[r]*hp);
      }
      uint32_t p0 = (uint32_t)hb[0] | ((uint32_t)hb[1]<<16);
      uint32_t p1 = (uint32_t)hb[2] | ((uint32_t)hb[3]<<16);
      uint32_t* hwd = (uint32_t*)(hstate + (st&3)*4096);
      __hip_atomic_store(hwd + di,     p0, __ATOMIC_RELAXED, __HIP_MEMORY_SCOPE_AGENT);
      __hip_atomic_store(hwd + di + 1, p1, __ATOMIC_RELAXED, __HIP_MEMORY_SCOPE_AGENT);
      uint32_t* sq = (uint32_t*)(hseq + ((size_t)c*SS + st)*DD + n0w);
      sq[0] = p0; sq[1] = p1;            // cached store: stays in L2
    }
    __syncthreads();                     // keep waves together across steps
  }
}

// --------------------------------------------------------------- launch -----
extern "C" void kernel_launch(void* const* d_in, const int* in_sizes, int n_in,
                              void* d_out, int out_size, void* d_ws, size_t ws_size,
                              hipStream_t stream)
{
  const float* x   = (const float*)d_in[0];
  const float* n1w = (const float*)d_in[1];
  const float* Wq  = (const float*)d_in[2];
  const float* bq  = (const float*)d_in[3];
  const float* Wk  = (const float*)d_in[4];
  const float* bk  = (const float*)d_in[5];
  const float* Wv  = (const float*)d_in[6];
  const float* bv  = (const float*)d_in[7];
  const float* Wz  = (const float*)d_in[8];
  const float* bz  = (const float*)d_in[9];
  const float* Wg_ = (const float*)d_in[10];
  const float* bg  = (const float*)d_in[11];
  const float* gdw = (const float*)d_in[12];
  const float* gdb = (const float*)d_in[13];
  const float* guw = (const float*)d_in[14];
  const float* gub = (const float*)d_in[15];
  const float* Wo  = (const float*)d_in[16];
  const float* bo  = (const float*)d_in[17];
  const float* n2w = (const float*)d_in[18];
  const float* f1w = (const float*)d_in[19];
  const float* f1b = (const float*)d_in[20];
  const float* f2w = (const float*)d_in[21];
  const float* f2b = (const float*)d_in[22];

  char* ws = (char*)d_ws;
  const size_t MB = (size_t)1<<20;
  ushort* Wqb  = (ushort*)(ws +  0*MB);
  ushort* Wkb  = (ushort*)(ws +  2*MB);
  ushort* Wvb  = (ushort*)(ws +  4*MB);
  ushort* Wzb  = (ushort*)(ws +  6*MB);
  ushort* Wob  = (ushort*)(ws +  8*MB);
  ushort* Wgb  = (ushort*)(ws + 10*MB);
  ushort* gdwb = (ushort*)(ws + 12*MB);
  ushort* guwb = (ushort*)(ws + 12*MB + (512<<10));
  ushort* f1wb = (ushort*)(ws + 13*MB);
  ushort* f2wb = (ushort*)(ws + 21*MB);
  ushort* xn   = (ushort*)(ws + 29*MB);
  ushort* qb   = (ushort*)(ws + 37*MB);
  ushort* kb   = (ushort*)(ws + 45*MB);
  ushort* vb   = (ushort*)(ws + 53*MB);
  ushort* zb16 = (ushort*)(ws + 61*MB);
  ushort* ff1  = (ushort*)(ws + 37*MB);   // aliases qb..zb16 (dead by then)
  ushort* t1   = (ushort*)(ws + 69*MB);
  ushort* hseq = (ushort*)(ws + 70*MB);
  ushort* aob  = (ushort*)(ws + 78*MB);
  float*  zb32 = (float*) (ws + 86*MB);
  float*  yf   = (float*) (ws + 86*MB);   // aliases zb32 (dead after scan)
  float*  gm32 = (float*) (ws +102*MB);
  ushort* hst  = (ushort*)(ws +118*MB);   // 4 x 4096 bf16 ring (32 KB)
  ushort* yn = xn;

  // 0. cast weights fp32 -> bf16
  cast_k<<<1024, 256, 0, stream>>>(Wq,  Wqb, 1048576);
  cast_k<<<1024, 256, 0, stream>>>(Wk,  Wkb, 1048576);
  cast_k<<<1024, 256, 0, stream>>>(Wv,  Wvb, 1048576);
  cast_k<<<1024, 256, 0, stream>>>(Wz,  Wzb, 1048576);
  cast_k<<<1024, 256, 0, stream>>>(Wo,  Wob, 1048576);
  cast_k<<<1024, 256, 0, stream>>>(Wg_, Wgb, 1048576);
  cast_k<<< 128, 256, 0, stream>>>(gdw, gdwb, 131072);
  cast_k<<< 128, 256, 0, stream>>>(guw, guwb, 131072);
  cast_k<<<4096, 256, 0, stream>>>(f1w, f1wb, 4194304);
  cast_k<<<4096, 256, 0, stream>>>(f2w, f2wb, 4194304);
  // 1. rmsnorm(x)
  rmsnorm_k<<<4096, 256, 0, stream>>>(x, n1w, xn);
  // 2. Q/K/V/Z projections
  gemm_bt<ACT_NONE,EPI_B16 ><<<dim3(32,8), 256, 0, stream>>>(xn, Wqb, bq, 1024, 1024, qb,  nullptr, nullptr, nullptr, nullptr);
  gemm_bt<ACT_NONE,EPI_B16 ><<<dim3(32,8), 256, 0, stream>>>(xn, Wkb, bk, 1024, 1024, kb,  nullptr, nullptr, nullptr, nullptr);
  gemm_bt<ACT_NONE,EPI_B16 ><<<dim3(32,8), 256, 0, stream>>>(xn, Wvb, bv, 1024, 1024, vb,  nullptr, nullptr, nullptr, nullptr);
  gemm_bt<ACT_NONE,EPI_DUAL><<<dim3(32,8), 256, 0, stream>>>(xn, Wzb, bz, 1024, 1024, zb16, zb32,   nullptr, nullptr, nullptr);
  // 3. gamma
  gemm_bt<ACT_RELU,EPI_B16><<<dim3(32,1), 256, 0, stream>>>(zb16, gdwb, gdb, 128, 1024, t1, nullptr, nullptr, nullptr, nullptr);
  gemm_bt<ACT_SIG ,EPI_F32><<<dim3(32,8), 256, 0, stream>>>(t1, guwb, gub, 1024, 128, nullptr, gm32, nullptr, nullptr, nullptr);
  // 4. attention
  attn_k<<<dim3(16,64), 256, 0, stream>>>(qb, kb, vb, aob);
  // 5. recurrence (ring pre-set to sentinel 0xFF)
  (void)hipMemsetAsync(hst, 0xFF, 32768, stream);
  scan_k<<<dim3(NBS), 256, 0, stream>>>(Wgb, bg, zb32, gm32, hseq, hst);
  // 6. y = x + ao@Wo.T+bo + hseq
  gemm_bt<ACT_NONE,EPI_Y><<<dim3(32,8), 256, 0, stream>>>(aob, Wob, bo, 1024, 1024, nullptr, yf, x, hseq, nullptr);
  // 7. FFN + out
  rmsnorm_k<<<4096, 256, 0, stream>>>(yf, n2w, yn);
  gemm_bt<ACT_GELU,EPI_B16><<<dim3(32,32), 256, 0, stream>>>(yn, f1wb, f1b, 4096, 1024, ff1, nullptr, nullptr, nullptr, nullptr);
  gemm_bt<ACT_NONE,EPI_OUT><<<dim3(32,8), 256, 0, stream>>>(ff1, f2wb, f2b, 1024, 4096, nullptr, (float*)d_out, nullptr, nullptr, yf);
}